// Round 5
// baseline (550.356 us; speedup 1.0000x reference)
//
#include <hip/hip_runtime.h>
#include <hip/hip_cooperative_groups.h>
#include <math.h>

namespace cg = cooperative_groups;

#define N_NODES 50000
#define IN_CH 256
#define N_REL 5
#define N_EDGES 800000
#define N_GLOB 20000   // LAST_GLOBALS - LAST_SENSES
#define N_SENSE 25000
#define N_OUT 45000
#define MAX_MATCH 256        // E[matches]=16; 256 is astronomically safe
#define GRID_BLOCKS 1024     // 4 blocks/CU co-resident (cooperative launch)
#define NWAVES (GRID_BLOCKS * 4)
#define N_OUT4 (N_OUT / 4)   // 11250 float4s
#define N_GLOB4 (N_GLOB / 4) // 5000 -> segment boundary float4-aligned
#define STAT_BLOCKS ((N_OUT4 + 255) / 256)   // 44

// ---------------- workspace layout (floats from base) ----------------
// x1acc : [0, 256)      atomic accumulator for pre-relu x1
// ip    : ints at float offset 256: [0]=match cnt, [1..5]=per-rel cnt,
//         [8..264)=src, [264..520)=type
// raw   : [1024, 46024) unnormalized logits (16B-aligned)

__global__ __launch_bounds__(256, 4)
void k_fused(const float* __restrict__ x,
             const int* __restrict__ ei,
             const int* __restrict__ et,
             const float* __restrict__ comp,
             const float* __restrict__ basis,
             const float* __restrict__ root,
             const float* __restrict__ bias,
             const float* __restrict__ Wg,
             const float* __restrict__ bg,
             const float* __restrict__ Ws,
             const float* __restrict__ bs,
             float* __restrict__ out,
             float* __restrict__ x1acc,
             int* __restrict__ ip,
             float* __restrict__ raw) {
    cg::grid_group grid = cg::this_grid();
    __shared__ float u[64];
    __shared__ float r1[256], r2[256];
    int tid = threadIdx.x, bid = blockIdx.x;

    // ---- Phase 0: zero accumulators (replaces memset launch) ----
    if (bid == 0) {
        x1acc[tid] = 0.f;
        if (tid < 8) ip[tid] = 0;
    }
    grid.sync();

    // ---- Phase 1: scan edges for dst == 0 (int4 over dst row) ----
    {
        int g = bid * 256 + tid;             // 262144 threads >= 200000 quads
        if (g < N_EDGES / 4) {
            int4 d = ((const int4*)(ei + N_EDGES))[g];
            int e = g * 4;
            int hit4 = (d.x == 0) | (d.y == 0) | (d.z == 0) | (d.w == 0);
            if (hit4) {
                #pragma unroll
                for (int q = 0; q < 4; ++q) {
                    int dv = (q == 0) ? d.x : (q == 1) ? d.y : (q == 2) ? d.z : d.w;
                    if (dv == 0) {
                        int t = et[e + q];
                        int p = atomicAdd(&ip[0], 1);
                        if (p < MAX_MATCH) {
                            ip[8 + p] = ei[e + q];           // src
                            ip[8 + MAX_MATCH + p] = t;       // type
                        }
                        atomicAdd(&ip[1 + t], 1);
                    }
                }
            }
        }
    }
    grid.sync();

    // ---- Phase 2: x1acc += sum_b u_b @ basis[b] + x[0] @ root + bias ----
    // 24 blocks = 6 matrices (5 basis + root) x 4 row-slices of 64.
    // Rows d0..d0+63 of a matvec need only u[d0..d0+63] (4KB x-gather slice).
    if (bid < 24) {
        int mat = bid >> 2;                  // 0..5
        int d0 = (bid & 3) * 64;
        if (tid < 64) {
            if (mat < 5) {
                int m = ip[0]; if (m > MAX_MATCH) m = MAX_MATCH;
                float acc = 0.f;
                for (int j = 0; j < m; ++j) {
                    int s = ip[8 + j];
                    int t = ip[8 + MAX_MATCH + j];
                    float scale = comp[t * N_REL + mat] /
                                  fmaxf((float)ip[1 + t], 1.0f);
                    acc += scale * x[(size_t)s * IN_CH + d0 + tid];
                }
                u[tid] = acc;
            } else {
                u[tid] = x[d0 + tid];        // root operand: x[0] slice
            }
        }
        __syncthreads();
        const float* M = ((mat < 5) ? (basis + (size_t)mat * IN_CH * IN_CH)
                                    : root) + (size_t)d0 * IN_CH;
        float acc = 0.f;
#pragma unroll 16
        for (int d = 0; d < 64; ++d) acc += u[d] * M[d * IN_CH + tid];
        if (mat == 5 && d0 == 0) acc += bias[tid];
        atomicAdd(&x1acc[tid], acc);
    }
    grid.sync();

    // ---- Phase 3: raw logits, wave-per-row grid-stride (46 MB stream) ----
    {
        int lane = tid & 63;
        int gw = bid * 4 + (tid >> 6);
        float4 xv = ((const float4*)x1acc)[lane];
        xv.x = fmaxf(xv.x, 0.f); xv.y = fmaxf(xv.y, 0.f);
        xv.z = fmaxf(xv.z, 0.f); xv.w = fmaxf(xv.w, 0.f);
        for (int row = gw; row < N_OUT; row += NWAVES) {
            const float4* wr;
            float b;
            if (row < N_GLOB) {
                wr = (const float4*)(Wg + (size_t)row * IN_CH);
                b = bg[row];
            } else {
                int r2i = row - N_GLOB;
                wr = (const float4*)(Ws + (size_t)r2i * IN_CH);
                b = bs[r2i];
            }
            float4 wv = wr[lane];
            float s = wv.x * xv.x + wv.y * xv.y + wv.z * xv.z + wv.w * xv.w;
#pragma unroll
            for (int off = 32; off > 0; off >>= 1) s += __shfl_down(s, off);
            if (lane == 0) raw[row] = s + b;
        }
    }
    grid.sync();

    // ---- Phase 4: log-softmax stats + normalize (blocks 0..43) ----
    if (bid >= STAT_BLOCKS) return;
    {
        const float4* o4 = (const float4*)raw;
        float mg = -3.4e38f, ms = -3.4e38f;
        for (int i = tid; i < N_OUT4; i += 256) {
            float4 v = o4[i];
            float m4 = fmaxf(fmaxf(v.x, v.y), fmaxf(v.z, v.w));
            if (i < N_GLOB4) mg = fmaxf(mg, m4); else ms = fmaxf(ms, m4);
        }
        r1[tid] = mg; r2[tid] = ms; __syncthreads();
        for (int h = 128; h > 0; h >>= 1) {
            if (tid < h) {
                r1[tid] = fmaxf(r1[tid], r1[tid + h]);
                r2[tid] = fmaxf(r2[tid], r2[tid + h]);
            }
            __syncthreads();
        }
        mg = r1[0]; ms = r2[0]; __syncthreads();
        float sg = 0.f, ss = 0.f;
        for (int i = tid; i < N_OUT4; i += 256) {
            float4 v = o4[i];
            if (i < N_GLOB4)
                sg += expf(v.x - mg) + expf(v.y - mg) +
                      expf(v.z - mg) + expf(v.w - mg);
            else
                ss += expf(v.x - ms) + expf(v.y - ms) +
                      expf(v.z - ms) + expf(v.w - ms);
        }
        r1[tid] = sg; r2[tid] = ss; __syncthreads();
        for (int h = 128; h > 0; h >>= 1) {
            if (tid < h) { r1[tid] += r1[tid + h]; r2[tid] += r2[tid + h]; }
            __syncthreads();
        }
        float zg = mg + logf(r1[0]);
        float zs = ms + logf(r2[0]);
        int i = bid * 256 + tid;
        if (i < N_OUT4) {
            float4 v = o4[i];
            float z = (i < N_GLOB4) ? zg : zs;
            v.x -= z; v.y -= z; v.z -= z; v.w -= z;
            ((float4*)out)[i] = v;
        }
    }
}

extern "C" void kernel_launch(void* const* d_in, const int* in_sizes, int n_in,
                              void* d_out, int out_size, void* d_ws, size_t ws_size,
                              hipStream_t stream) {
    const float* x     = (const float*)d_in[0];
    const int*   ei    = (const int*)  d_in[1];
    const int*   et    = (const int*)  d_in[2];
    const float* comp  = (const float*)d_in[3];
    const float* basis = (const float*)d_in[4];
    const float* root  = (const float*)d_in[5];
    const float* bias  = (const float*)d_in[6];
    const float* Wg    = (const float*)d_in[7];
    const float* bg    = (const float*)d_in[8];
    const float* Wsn   = (const float*)d_in[9];
    const float* bs    = (const float*)d_in[10];
    float* out = (float*)d_out;

    float* base  = (float*)d_ws;
    float* x1acc = base;                 // 256
    int*   ip    = (int*)(base + 256);   // 8 + 2*MAX_MATCH ints
    float* raw   = base + 1024;          // 45000, 16B-aligned

    void* args[] = {
        (void*)&x, (void*)&ei, (void*)&et, (void*)&comp, (void*)&basis,
        (void*)&root, (void*)&bias, (void*)&Wg, (void*)&bg, (void*)&Wsn,
        (void*)&bs, (void*)&out, (void*)&x1acc, (void*)&ip, (void*)&raw
    };
    hipLaunchCooperativeKernel((const void*)k_fused, dim3(GRID_BLOCKS),
                               dim3(256), args, 0, stream);
}

// Round 6
// 162.149 us; speedup vs baseline: 3.3941x; 3.3941x over previous
//
#include <hip/hip_runtime.h>
#include <math.h>

#define N_NODES 50000
#define IN_CH 256
#define N_REL 5
#define N_EDGES 800000
#define N_GLOB 20000   // LAST_GLOBALS - LAST_SENSES
#define N_SENSE 25000
#define N_OUT 45000
#define MAX_MATCH 256             // E[matches]=16; 256 is astronomically safe
#define NBLK_LOGITS (N_OUT / 4)   // 11250 blocks, 4 rows each (exact)
#define NBLK_GLOB (N_GLOB / 4)    // 5000 -> partial-array segment split exact
#define N_OUT4 (N_OUT / 4)        // 11250 float4 output chunks
#define N_GLOB4 (N_GLOB / 4)
#define STAT_BLOCKS ((N_OUT4 + 255) / 256)   // 44

// ---------------- workspace layout (floats from base) ----------------
// x1acc : [0, 256)      atomic accumulator for pre-relu x1   (memset 0)
// ip    : ints at float offset 256: [0]=match cnt, [1..5]=per-rel cnt,
//         [8..264)=src, [264..520)=type                      (ip[0..7] memset 0)
// pmax  : [1024, 12274)   per-logits-block max
// psum  : [12274, 23524)  per-logits-block sum(exp(.-max))
// memset covers floats [0, 264) = 1056 bytes.

// ---- scan: collect edges with dst == 0 (int4 over the dst row) ----
__global__ void k_scan(const int* __restrict__ ei,
                       const int* __restrict__ et,
                       int* __restrict__ ip) {
    int g = blockIdx.x * 256 + threadIdx.x;
    if (g >= N_EDGES / 4) return;
    int4 d = ((const int4*)(ei + N_EDGES))[g];
    int e = g * 4;
#pragma unroll
    for (int q = 0; q < 4; ++q) {
        int dv = (q == 0) ? d.x : (q == 1) ? d.y : (q == 2) ? d.z : d.w;
        if (dv == 0) {
            int t = et[e + q];
            int p = atomicAdd(&ip[0], 1);
            if (p < MAX_MATCH) {
                ip[8 + p] = ei[e + q];           // src
                ip[8 + MAX_MATCH + p] = t;       // type
            }
            atomicAdd(&ip[1 + t], 1);
        }
    }
}

// ---- x1: x1acc += sum_b u_b @ basis[b] + x[0] @ root + bias ----
// 24 blocks = 6 matrices (5 basis + root) x 4 K-slices of 64 rows.
// Rows d0..d0+63 of a matvec need only u[d0..d0+63], so the x-gather is a
// 64-float slice. Gather is parallel: wave g (of 4) handles edges j = g,
// g+4, ... -> ~4 dependent rounds instead of 16; j is wave-uniform (scalar
// ip loads). LDS-reduce the 4 partials, then 256-thread matvec on the slice.
__global__ void k_x1(const float* __restrict__ x,
                     const float* __restrict__ comp,
                     const float* __restrict__ basis,
                     const float* __restrict__ root,
                     const float* __restrict__ bias,
                     const int* __restrict__ ip,
                     float* __restrict__ x1acc) {
    __shared__ float part[4][64];
    __shared__ float u[64];
    int tid = threadIdx.x;
    int f = tid & 63, g = tid >> 6;          // g == wave id
    int mat = blockIdx.x >> 2;               // 0..5
    int d0 = (blockIdx.x & 3) * 64;
    if (mat < 5) {
        int m = ip[0]; if (m > MAX_MATCH) m = MAX_MATCH;
        float acc = 0.f;
        for (int j = g; j < m; j += 4) {
            int s = ip[8 + j];
            int t = ip[8 + MAX_MATCH + j];
            float scale = comp[t * N_REL + mat] /
                          fmaxf((float)ip[1 + t], 1.0f);
            acc += scale * x[(size_t)s * IN_CH + d0 + f];
        }
        part[g][f] = acc;
        __syncthreads();
        if (tid < 64) u[f] = part[0][f] + part[1][f] + part[2][f] + part[3][f];
    } else {
        if (tid < 64) u[f] = x[d0 + tid];    // root operand: x[0] slice
    }
    __syncthreads();
    const float* M = ((mat < 5) ? (basis + (size_t)mat * IN_CH * IN_CH)
                                : root) + (size_t)d0 * IN_CH;
    float acc = 0.f;
#pragma unroll 16
    for (int d = 0; d < 64; ++d) acc += u[d] * M[d * IN_CH + tid];
    if (mat == 5 && d0 == 0) acc += bias[tid];
    atomicAdd(&x1acc[tid], acc);
}

// ---- logits: 4 rows per block (1 wave each), raw logits -> d_out,
// fused per-block (max, sumexp) partials ----
__global__ void k_logits(const float* __restrict__ Wg,
                         const float* __restrict__ bg,
                         const float* __restrict__ Ws,
                         const float* __restrict__ bs,
                         const float* __restrict__ x1acc,
                         float* __restrict__ out,
                         float* __restrict__ pmax,
                         float* __restrict__ psum) {
    __shared__ float sx[IN_CH];
    __shared__ float sl[4];
    int tid = threadIdx.x;
    sx[tid] = fmaxf(x1acc[tid], 0.f);        // relu on read
    __syncthreads();
    int lane = tid & 63, w = tid >> 6;
    int row = blockIdx.x * 4 + w;            // 4*11250 == N_OUT, no guard
    const float4* wr;
    float b;
    if (row < N_GLOB) {
        wr = (const float4*)(Wg + (size_t)row * IN_CH);
        b = bg[row];
    } else {
        int r2 = row - N_GLOB;
        wr = (const float4*)(Ws + (size_t)r2 * IN_CH);
        b = bs[r2];
    }
    float4 wv = wr[lane];
    float4 xv = ((const float4*)sx)[lane];
    float s = wv.x * xv.x + wv.y * xv.y + wv.z * xv.z + wv.w * xv.w;
#pragma unroll
    for (int off = 32; off > 0; off >>= 1) s += __shfl_down(s, off);
    if (lane == 0) { float l = s + b; out[row] = l; sl[w] = l; }
    __syncthreads();
    if (tid == 0) {
        float m4 = fmaxf(fmaxf(sl[0], sl[1]), fmaxf(sl[2], sl[3]));
        float s4 = expf(sl[0] - m4) + expf(sl[1] - m4) +
                   expf(sl[2] - m4) + expf(sl[3] - m4);
        pmax[blockIdx.x] = m4;
        psum[blockIdx.x] = s4;
    }
}

// ---- fused stats+normalize: 44 blocks; each redundantly LSE-merges the
// 90 KB L2-hot partials for both segments, then normalizes its own 256
// float4 chunks of d_out in place (no cross-block read of another's rows).
__global__ void k_statsfinal(const float* __restrict__ pmax,
                             const float* __restrict__ psum,
                             float* __restrict__ out) {
    __shared__ float rmg[256], rsg[256], rms[256], rss[256];
    int tid = threadIdx.x;
    float mg = -3.4e38f, sg = 0.f, ms = -3.4e38f, ss = 0.f;
    for (int i = tid; i < NBLK_LOGITS; i += 256) {
        float mi = pmax[i], si = psum[i];
        if (i < NBLK_GLOB) {
            float M = fmaxf(mg, mi);
            sg = sg * expf(mg - M) + si * expf(mi - M); mg = M;
        } else {
            float M = fmaxf(ms, mi);
            ss = ss * expf(ms - M) + si * expf(mi - M); ms = M;
        }
    }
    rmg[tid] = mg; rsg[tid] = sg; rms[tid] = ms; rss[tid] = ss;
    __syncthreads();
    for (int h = 128; h > 0; h >>= 1) {
        if (tid < h) {
            float m2 = rmg[tid + h], s2 = rsg[tid + h];
            float M = fmaxf(rmg[tid], m2);
            rsg[tid] = rsg[tid] * expf(rmg[tid] - M) + s2 * expf(m2 - M);
            rmg[tid] = M;
            m2 = rms[tid + h]; s2 = rss[tid + h];
            M = fmaxf(rms[tid], m2);
            rss[tid] = rss[tid] * expf(rms[tid] - M) + s2 * expf(m2 - M);
            rms[tid] = M;
        }
        __syncthreads();
    }
    float zg = rmg[0] + logf(rsg[0]);
    float zs = rms[0] + logf(rss[0]);
    int i = blockIdx.x * 256 + tid;
    if (i < N_OUT4) {
        float4 v = ((const float4*)out)[i];
        float z = (i < N_GLOB4) ? zg : zs;
        v.x -= z; v.y -= z; v.z -= z; v.w -= z;
        ((float4*)out)[i] = v;
    }
}

extern "C" void kernel_launch(void* const* d_in, const int* in_sizes, int n_in,
                              void* d_out, int out_size, void* d_ws, size_t ws_size,
                              hipStream_t stream) {
    const float* x     = (const float*)d_in[0];
    const int*   ei    = (const int*)  d_in[1];
    const int*   et    = (const int*)  d_in[2];
    const float* comp  = (const float*)d_in[3];
    const float* basis = (const float*)d_in[4];
    const float* root  = (const float*)d_in[5];
    const float* bias  = (const float*)d_in[6];
    const float* Wg    = (const float*)d_in[7];
    const float* bg    = (const float*)d_in[8];
    const float* Wsn   = (const float*)d_in[9];
    const float* bs    = (const float*)d_in[10];
    float* out = (float*)d_out;

    float* base  = (float*)d_ws;
    float* x1acc = base;                 // 256
    int*   ip    = (int*)(base + 256);   // 8 + 2*MAX_MATCH ints
    float* pmax  = base + 1024;          // 11250
    float* psum  = base + 12274;         // 11250

    hipMemsetAsync(d_ws, 0, 1056, stream);   // x1acc + ip[0..7]
    k_scan      <<<(N_EDGES / 4 + 255) / 256, 256, 0, stream>>>(ei, et, ip);
    k_x1        <<<24, 256, 0, stream>>>(x, comp, basis, root, bias, ip, x1acc);
    k_logits    <<<NBLK_LOGITS, 256, 0, stream>>>(Wg, bg, Wsn, bs, x1acc, out, pmax, psum);
    k_statsfinal<<<STAT_BLOCKS, 256, 0, stream>>>(pmax, psum, out);
}